// Round 1
// baseline (300.649 us; speedup 1.0000x reference)
//
#include <hip/hip_runtime.h>
#include <math.h>

#define NN 1024   // nodes
#define DD 128    // dim
#define BB 1024   // graphs

__device__ __forceinline__ float waveReduceSum(float v) {
#pragma unroll
  for (int off = 32; off > 0; off >>= 1) v += __shfl_xor(v, off);
  return v;
}
__device__ __forceinline__ float waveReduceMax(float v) {
#pragma unroll
  for (int off = 32; off > 0; off >>= 1) v = fmaxf(v, __shfl_xor(v, off));
  return v;
}

// A: L2-normalize rows of node_embedding (rows 0..NN-1) and graph_embedding
// (rows NN..NN+BB-1). One wave per row, float2 per lane (128 floats/row).
__global__ __launch_bounds__(64) void normalize_kernel(
    const float* __restrict__ ne, const float* __restrict__ ge,
    float* __restrict__ ne_n, float* __restrict__ ge_n) {
  int row = blockIdx.x;
  int lane = threadIdx.x;
  const float* src;
  float* dst;
  if (row < NN) { src = ne + (size_t)row * DD; dst = ne_n + (size_t)row * DD; }
  else { src = ge + (size_t)(row - NN) * DD; dst = ge_n + (size_t)(row - NN) * DD; }
  float2 v = ((const float2*)src)[lane];
  float ss = v.x * v.x + v.y * v.y;
  ss = waveReduceSum(ss);
  float scale = 1.0f / fmaxf(sqrtf(ss), 1e-12f);
  float2 o;
  o.x = v.x * scale;
  o.y = v.y * scale;
  ((float2*)dst)[lane] = o;
}

// B: per-row max and sum(exp(x-max)) of graph_metric. One wave per row.
__global__ __launch_bounds__(64) void gm_stats_kernel(
    const float* __restrict__ gm, float* __restrict__ gm_max,
    float* __restrict__ gm_den) {
  int row = blockIdx.x;
  int lane = threadIdx.x;
  const float4* r = (const float4*)(gm + (size_t)row * BB);
  float vals[16];
  float m = -INFINITY;
#pragma unroll
  for (int k = 0; k < 4; ++k) {
    float4 v = r[lane + 64 * k];
    vals[k * 4 + 0] = v.x; vals[k * 4 + 1] = v.y;
    vals[k * 4 + 2] = v.z; vals[k * 4 + 3] = v.w;
    m = fmaxf(m, fmaxf(fmaxf(v.x, v.y), fmaxf(v.z, v.w)));
  }
  m = waveReduceMax(m);
  float s = 0.f;
#pragma unroll
  for (int t = 0; t < 16; ++t) s += expf(vals[t] - m);
  s = waveReduceSum(s);
  if (lane == 0) { gm_max[row] = m; gm_den[row] = s; }
}

// Shared pattern for C/D: block i computes logits[j] = dot(X[j], X[i]) for all
// j, 16-lane group per row (coalesced 512B/row), then block-wide lse.
// C: node loss partial = logits[i] - lse_i.
__global__ __launch_bounds__(256) void node_loss_kernel(
    const float* __restrict__ nen, float* __restrict__ node_partial) {
  int i = blockIdx.x;
  int tid = threadIdx.x;
  int lane = tid & 63, wid = tid >> 6;
  int g = lane >> 4, gl = lane & 15;
  __shared__ float q[DD];
  __shared__ float logits[NN];
  __shared__ float red[8];
  if (tid < DD) q[tid] = nen[(size_t)i * DD + tid];
  __syncthreads();
  const float4* qv = (const float4*)q;
  float4 b0 = qv[gl * 2], b1 = qv[gl * 2 + 1];
#pragma unroll 4
  for (int p = 0; p < 64; ++p) {
    int j = p * 16 + wid * 4 + g;
    const float4* row = (const float4*)(nen + (size_t)j * DD);
    float4 a0 = row[gl * 2], a1 = row[gl * 2 + 1];
    float acc = a0.x * b0.x + a0.y * b0.y + a0.z * b0.z + a0.w * b0.w +
                a1.x * b1.x + a1.y * b1.y + a1.z * b1.z + a1.w * b1.w;
    acc += __shfl_xor(acc, 1);
    acc += __shfl_xor(acc, 2);
    acc += __shfl_xor(acc, 4);
    acc += __shfl_xor(acc, 8);
    if (gl == 0) logits[j] = acc;
  }
  __syncthreads();
  float lv[4];
  float m = -INFINITY;
#pragma unroll
  for (int k = 0; k < 4; ++k) {
    lv[k] = logits[tid + 256 * k];
    m = fmaxf(m, lv[k]);
  }
  m = waveReduceMax(m);
  if (lane == 0) red[wid] = m;
  __syncthreads();
  float M = fmaxf(fmaxf(red[0], red[1]), fmaxf(red[2], red[3]));
  float s = 0.f;
#pragma unroll
  for (int k = 0; k < 4; ++k) s += expf(lv[k] - M);
  s = waveReduceSum(s);
  if (lane == 0) red[4 + wid] = s;
  __syncthreads();
  float S = red[4] + red[5] + red[6] + red[7];
  if (tid == 0) node_partial[i] = logits[i] - (M + logf(S));
}

// D: graph logits (written to out), lse, and weighted partial
// sum_j (gm[i,j] + gm[j,i]) * lp[i,j]. graph_logits is symmetric (bitwise,
// same reduction order), so lpT == lp.
__global__ __launch_bounds__(256) void graph_loss_kernel(
    const float* __restrict__ gen, const float* __restrict__ gm,
    const float* __restrict__ gm_max, const float* __restrict__ gm_den,
    float* __restrict__ out_logits, float* __restrict__ graph_partial) {
  int i = blockIdx.x;
  int tid = threadIdx.x;
  int lane = tid & 63, wid = tid >> 6;
  int g = lane >> 4, gl = lane & 15;
  __shared__ float q[DD];
  __shared__ float logits[BB];
  __shared__ float red[8];
  if (tid < DD) q[tid] = gen[(size_t)i * DD + tid];
  __syncthreads();
  const float4* qv = (const float4*)q;
  float4 b0 = qv[gl * 2], b1 = qv[gl * 2 + 1];
#pragma unroll 4
  for (int p = 0; p < 64; ++p) {
    int j = p * 16 + wid * 4 + g;
    const float4* row = (const float4*)(gen + (size_t)j * DD);
    float4 a0 = row[gl * 2], a1 = row[gl * 2 + 1];
    float acc = a0.x * b0.x + a0.y * b0.y + a0.z * b0.z + a0.w * b0.w +
                a1.x * b1.x + a1.y * b1.y + a1.z * b1.z + a1.w * b1.w;
    acc += __shfl_xor(acc, 1);
    acc += __shfl_xor(acc, 2);
    acc += __shfl_xor(acc, 4);
    acc += __shfl_xor(acc, 8);
    if (gl == 0) logits[j] = acc;
  }
  __syncthreads();
  float lv[4];
  float m = -INFINITY;
#pragma unroll
  for (int k = 0; k < 4; ++k) {
    lv[k] = logits[tid + 256 * k];
    m = fmaxf(m, lv[k]);
    out_logits[(size_t)i * BB + tid + 256 * k] = lv[k];  // coalesced store
  }
  m = waveReduceMax(m);
  if (lane == 0) red[wid] = m;
  __syncthreads();
  float M = fmaxf(fmaxf(red[0], red[1]), fmaxf(red[2], red[3]));
  float s = 0.f;
#pragma unroll
  for (int k = 0; k < 4; ++k) s += expf(lv[k] - M);
  s = waveReduceSum(s);
  if (lane == 0) red[4 + wid] = s;
  __syncthreads();
  float S = red[4] + red[5] + red[6] + red[7];
  float lse = M + logf(S);
  float gmx_i = gm_max[i];
  float inv_i = 1.0f / gm_den[i];
  float c = 0.f;
#pragma unroll
  for (int k = 0; k < 4; ++k) {
    int j = tid + 256 * k;
    float lp = lv[k] - lse;
    float wij = expf(gm[(size_t)i * BB + j] - gmx_i) * inv_i;
    float wji = expf(gm[(size_t)j * BB + i] - gm_max[j]) / gm_den[j];
    c += (wij + wji) * lp;
  }
  c = waveReduceSum(c);
  __syncthreads();  // red reuse
  if (lane == 0) red[wid] = c;
  __syncthreads();
  if (tid == 0) graph_partial[i] = red[0] + red[1] + red[2] + red[3];
}

// E: pairwise concat stream. One wave per 1 KB output row r = i*NN + j:
// row = [ne_n[i] (128) | ne_n[j] (128)]. Region base is only 4B-aligned
// (out+1048579) so use 4 coalesced scalar-dword stores (256B each).
__global__ __launch_bounds__(256) void pairwise_kernel(
    const float* __restrict__ nen, float* __restrict__ outp) {
  size_t row = (size_t)blockIdx.x * 4 + (threadIdx.x >> 6);
  int lane = threadIdx.x & 63;
  int i = (int)(row >> 10);
  int j = (int)(row & 1023);
  float v0 = nen[(size_t)i * DD + lane];
  float v1 = nen[(size_t)i * DD + 64 + lane];
  float v2 = nen[(size_t)j * DD + lane];
  float v3 = nen[(size_t)j * DD + 64 + lane];
  float* dst = outp + row * 256;
  dst[lane] = v0;
  dst[64 + lane] = v1;
  dst[128 + lane] = v2;
  dst[192 + lane] = v3;
}

// F: deterministic final reduce of the 1024-element partial arrays.
__global__ __launch_bounds__(256) void final_kernel(
    const float* __restrict__ node_partial,
    const float* __restrict__ graph_partial, float* __restrict__ out) {
  int tid = threadIdx.x;
  int lane = tid & 63, wid = tid >> 6;
  __shared__ float red[8];
  float ns = 0.f, gs = 0.f;
#pragma unroll
  for (int k = 0; k < 4; ++k) {
    ns += node_partial[tid + 256 * k];
    gs += graph_partial[tid + 256 * k];
  }
  ns = waveReduceSum(ns);
  gs = waveReduceSum(gs);
  if (lane == 0) { red[wid] = ns; red[4 + wid] = gs; }
  __syncthreads();
  if (tid == 0) {
    float nsum = red[0] + red[1] + red[2] + red[3];
    float gsum = red[4] + red[5] + red[6] + red[7];
    float node_loss = -nsum / (float)NN;
    float graph_loss = -gsum / (float)BB;
    float loss = 0.5f * node_loss + 0.5f * graph_loss;
    out[0] = loss;
    out[1] = node_loss;
    out[2] = graph_loss;
  }
}

extern "C" void kernel_launch(void* const* d_in, const int* in_sizes, int n_in,
                              void* d_out, int out_size, void* d_ws,
                              size_t ws_size, hipStream_t stream) {
  const float* ne = (const float*)d_in[0];   // [1024,128]
  const float* ge = (const float*)d_in[1];   // [1024,128]
  const float* gm = (const float*)d_in[2];   // [1024,1024]
  float* out = (float*)d_out;
  float* ws = (float*)d_ws;

  // ws layout (floats): ~1.04 MB total
  float* ne_n = ws;                    // 131072
  float* ge_n = ws + 131072;           // 131072
  float* gm_max = ws + 262144;         // 1024
  float* gm_den = ws + 263168;         // 1024
  float* node_partial = ws + 264192;   // 1024
  float* graph_partial = ws + 265216;  // 1024

  float* out_logits = out + 3;                       // [1024,1024]
  float* out_pair = out + 3 + (size_t)NN * NN;       // [1024*1024, 256]

  hipLaunchKernelGGL(normalize_kernel, dim3(NN + BB), dim3(64), 0, stream,
                     ne, ge, ne_n, ge_n);
  hipLaunchKernelGGL(gm_stats_kernel, dim3(BB), dim3(64), 0, stream,
                     gm, gm_max, gm_den);
  hipLaunchKernelGGL(node_loss_kernel, dim3(NN), dim3(256), 0, stream,
                     ne_n, node_partial);
  hipLaunchKernelGGL(graph_loss_kernel, dim3(BB), dim3(256), 0, stream,
                     ge_n, gm, gm_max, gm_den, out_logits, graph_partial);
  hipLaunchKernelGGL(pairwise_kernel, dim3((NN * NN) / 4), dim3(256), 0,
                     stream, ne_n, out_pair);
  hipLaunchKernelGGL(final_kernel, dim3(1), dim3(256), 0, stream,
                     node_partial, graph_partial, out);
}